// Round 3
// baseline (30751.959 us; speedup 1.0000x reference)
//
#include <hip/hip_runtime.h>

// ShapeWeaverDecoder: 2-layer LSTM decoder, T=2048 steps, B=32, U=256.
// Round-3: self-validating 32B records (data+checksum) through MALL replace the
// flag+ring protocol: one poll == one gather, no ordering fences anywhere.
//   grid = 256 blocks x 512 threads (8 waves), 84KB LDS => 1 block/CU.
//   blocks [0,128):  layer-1. block=(half,slice): 4 units, batches [half*16,+16).
//                    R1 slice in 64 VGPRs/lane; also computes out-dense x.
//   blocks [128,256): layer-2. K2+R2 slices in 128 VGPRs/lane.
// Record(ring, step k, batch b, slice sl) = [h0,h1,h2,h3, chk] where
// chk = ((((h0+h1)+h2)+h3)+k) with identical rounding on both sides; consumer
// accepts on bit-exact match. Stale (tag differs by >=2) or torn reads fail.
// Ring depth 2 is safe: publishing h[s+2] transitively requires every consumer
// of h[s] to have consumed it. Big dots are computed on stale-available data
// BEFORE polling the fresh dependency, keeping the inter-block chain short.

#define TSTEPS 2048
#define UNITS  256
#define NB     32
#define NSL    64
#define NTHR   512

typedef float f4 __attribute__((ext_vector_type(4)));

constexpr int CH   = 72;              // LDS chunk stride (floats): conflict-free broadcast
constexpr int VECF = 4 * CH;          // one staged 256-vector
constexpr int BUFW = 4 * VECF;        // per-wave staging (4 vectors)
constexpr int SMEM_BYTES = 84 * 1024; // force 1 block/CU
constexpr int RECF = 8;               // floats per record (32B)

__device__ __forceinline__ float sigm(float x) { return 1.f / (1.f + expf(-x)); }

// Bitwise-deterministic checksum: both sides must use this exact chain.
__device__ __forceinline__ float mk_chk(float a, float b, float c, float d, float t) {
  return __fadd_rn(__fadd_rn(__fadd_rn(__fadd_rn(a, b), c), d), t);
}

// Device-scope (MALL) coherent record access. No fences needed: validation is
// value-based, so visibility order between the two stores is irrelevant.
__device__ __forceinline__ void load_rec(const float* p, f4& a, float& chk) {
  asm volatile("global_load_dwordx4 %0, %2, off sc0 sc1\n\t"
               "global_load_dword %1, %2, off offset:16 sc0 sc1\n\t"
               "s_waitcnt vmcnt(0)"
               : "=&v"(a), "=&v"(chk) : "v"(p) : "memory");
}
__device__ __forceinline__ void store_rec(float* p, const f4& d, float chk) {
  asm volatile("global_store_dwordx4 %0, %1, off sc0 sc1\n\t"
               "global_store_dword %0, %2, off offset:16 sc0 sc1"
               :: "v"(p), "v"(d), "v"(chk) : "memory");
}

// Poll two records (one per batch) until every lane has validated both.
// Bounded: on guard trip returns false and all later polls fall through fast.
__device__ __forceinline__ bool poll2(const float* p0, const float* p1, float tag,
                                      f4& d0, f4& d1, bool ok) {
  if (!ok) return false;
  bool v0 = false, v1 = false;
  int it = 0;
  for (;;) {
    if (!v0) {
      f4 a; float cc; load_rec(p0, a, cc);
      if (__float_as_uint(cc) == __float_as_uint(mk_chk(a.x, a.y, a.z, a.w, tag))) { d0 = a; v0 = true; }
    }
    if (!v1) {
      f4 a; float cc; load_rec(p1, a, cc);
      if (__float_as_uint(cc) == __float_as_uint(mk_chk(a.x, a.y, a.z, a.w, tag))) { d1 = a; v1 = true; }
    }
    if (__all(v0 && v1)) return true;
    if (++it > (1 << 18)) return false;
    if (it > 16) __builtin_amdgcn_s_sleep(1);
  }
}

// Publish one slice record for h*[k] (tag k). hn meaningful on lanes 0-3.
__device__ __forceinline__ void publish(float* ring, int k, int b, int slice,
                                        int lane, float hn) {
  const float h0 = __shfl(hn, 0), h1 = __shfl(hn, 1),
              h2 = __shfl(hn, 2), h3 = __shfl(hn, 3);
  const float chk = mk_chk(h0, h1, h2, h3, (float)k);
  if (lane == 0) {
    f4 d; d.x = h0; d.y = h1; d.z = h2; d.w = h3;
    store_rec(ring + (((k & 1) * NB + b) * NSL + slice) * RECF, d, chk);
  }
}

__device__ __forceinline__ const float* recp(const float* ring, int k, int b, int sl) {
  return ring + (((k & 1) * NB + b) * NSL + sl) * RECF;
}

__global__ __launch_bounds__(NTHR) void swd_kernel(
    const float* __restrict__ ctx, const float* __restrict__ Wc, const float* __restrict__ bc,
    const float* __restrict__ K1, const float* __restrict__ R1, const float* __restrict__ b1,
    const float* __restrict__ K2, const float* __restrict__ R2, const float* __restrict__ b2,
    const float* __restrict__ Wo, const float* __restrict__ bo,
    float* __restrict__ dout, float* __restrict__ ring1, float* __restrict__ ring2)
{
  extern __shared__ float sm[];
  const int wgid  = blockIdx.x;
  const int layer = wgid >> 7;
  const int half  = (wgid >> 6) & 1;
  const int slice = wgid & 63;
  const int tid = threadIdx.x, lane = tid & 63, wid = tid >> 6;
  const int c = lane & 15, kk = lane >> 4, q = c >> 2, u = c & 3;
  const int gc = q * UNITS + slice * 4 + u;   // keras gate-major column
  const int b0 = half * 16 + wid * 2, b1v = b0 + 1;
  float* buf = sm + wid * BUFW;               // wave-private staging
  bool ok = true;

  if (layer == 0) {
    // ---------------- layer-1 blocks ----------------
    float w1[64];
    #pragma unroll
    for (int j = 0; j < 64; ++j) w1[j] = R1[(64 * kk + j) * 1024 + gc];
    const float k1a = K1[gc], k1b = K1[1024 + gc], bb1 = b1[gc];
    float wo0[4], wo1[4];
    #pragma unroll
    for (int m = 0; m < 4; ++m) {
      wo0[m] = Wo[(4 * lane + m) * 2];
      wo1[m] = Wo[(4 * lane + m) * 2 + 1];
    }
    const float bo0 = bo[0], bo1 = bo[1];

    // init: publish h1[0] = relu(ctx @ Wc + bc) slice, tag 0
    #pragma unroll
    for (int bi = 0; bi < 2; ++bi) {
      const int b = b0 + bi;
      float hv[4];
      #pragma unroll
      for (int uu = 0; uu < 4; ++uu) {
        float p = 0.f;
        const float* cb = ctx + b * 512;
        const float* wc = Wc + slice * 4 + uu;
        #pragma unroll
        for (int m = 0; m < 8; ++m) p = fmaf(cb[lane * 8 + m], wc[(lane * 8 + m) * UNITS], p);
        #pragma unroll
        for (int d = 32; d; d >>= 1) p += __shfl_down(p, d);
        hv[uu] = fmaxf(p + bc[slice * 4 + uu], 0.f);   // valid on lane 0
      }
      const float chk = mk_chk(hv[0], hv[1], hv[2], hv[3], 0.f);
      if (lane == 0) {
        f4 d; d.x = hv[0]; d.y = hv[1]; d.z = hv[2]; d.w = hv[3];
        store_rec(ring1 + ((0 * NB + b) * NSL + slice) * RECF, d, chk);
      }
    }

    float c1a = 0.f, c1b = 0.f;          // cell state, lanes 0-3 meaningful
    float* bufA0 = buf;
    float* bufA1 = buf + VECF;
    for (int s = 0; s < TSTEPS; ++s) {
      // gather h1[s] (stale-available) and stage
      f4 d0, d1;
      ok = poll2(recp(ring1, s, b0, lane), recp(ring1, s, b1v, lane), (float)s, d0, d1, ok);
      *(f4*)(bufA0 + kk * CH + 4 * c) = d0;
      *(f4*)(bufA1 + kk * CH + 4 * c) = d1;
      // big dots while h2[s] is still in flight
      float ax0 = 0.f, ay0 = 0.f, az0 = 0.f, aw0 = 0.f;
      float ax1 = 0.f, ay1 = 0.f, az1 = 0.f, aw1 = 0.f;
      #pragma unroll
      for (int j = 0; j < 16; ++j) {
        const f4 h0 = *(const f4*)(bufA0 + kk * CH + 4 * j);
        const f4 h1 = *(const f4*)(bufA1 + kk * CH + 4 * j);
        ax0 = fmaf(w1[4 * j + 0], h0.x, ax0); ay0 = fmaf(w1[4 * j + 1], h0.y, ay0);
        az0 = fmaf(w1[4 * j + 2], h0.z, az0); aw0 = fmaf(w1[4 * j + 3], h0.w, aw0);
        ax1 = fmaf(w1[4 * j + 0], h1.x, ax1); ay1 = fmaf(w1[4 * j + 1], h1.y, ay1);
        az1 = fmaf(w1[4 * j + 2], h1.z, az1); aw1 = fmaf(w1[4 * j + 3], h1.w, aw1);
      }
      float part0 = (ax0 + ay0) + (az0 + aw0);
      float part1 = (ax1 + ay1) + (az1 + aw1);
      part0 += __shfl_down(part0, 16); part0 += __shfl_down(part0, 32);
      part1 += __shfl_down(part1, 16); part1 += __shfl_down(part1, 32);
      // fresh dependency: h2[s] -> x = out[s-1]
      float x00 = 0.5f, x01 = 0.5f, x10 = 0.5f, x11 = 0.5f;
      if (s > 0) {
        f4 g0, g1;
        ok = poll2(recp(ring2, s, b0, lane), recp(ring2, s, b1v, lane), (float)s, g0, g1, ok);
        float po00 = g0.x * wo0[0] + g0.y * wo0[1] + g0.z * wo0[2] + g0.w * wo0[3];
        float po01 = g0.x * wo1[0] + g0.y * wo1[1] + g0.z * wo1[2] + g0.w * wo1[3];
        float po10 = g1.x * wo0[0] + g1.y * wo0[1] + g1.z * wo0[2] + g1.w * wo0[3];
        float po11 = g1.x * wo1[0] + g1.y * wo1[1] + g1.z * wo1[2] + g1.w * wo1[3];
        #pragma unroll
        for (int d = 1; d < 64; d <<= 1) {
          po00 += __shfl_xor(po00, d); po01 += __shfl_xor(po01, d);
          po10 += __shfl_xor(po10, d); po11 += __shfl_xor(po11, d);
        }
        x00 = sigm(po00 + bo0); x01 = sigm(po01 + bo1);
        x10 = sigm(po10 + bo0); x11 = sigm(po11 + bo1);
        if (slice == 0 && lane == 0) {
          *(float2*)(dout + (b0  * TSTEPS + s - 1) * 2) = make_float2(x00, x01);
          *(float2*)(dout + (b1v * TSTEPS + s - 1) * 2) = make_float2(x10, x11);
        }
      }
      // finalize + publish h1[s+1]
      {
        const float z = part0 + x00 * k1a + x01 * k1b + bb1;
        const float act = (q == 2) ? tanhf(z) : sigm(z);
        const float gi = __shfl(act, u),     gf = __shfl(act, 4 + u),
                    gg = __shfl(act, 8 + u), go = __shfl(act, 12 + u);
        const float cn = gf * c1a + gi * gg;
        const float hn = go * tanhf(cn);
        c1a = cn;
        publish(ring1, s + 1, b0, slice, lane, hn);
      }
      {
        const float z = part1 + x10 * k1a + x11 * k1b + bb1;
        const float act = (q == 2) ? tanhf(z) : sigm(z);
        const float gi = __shfl(act, u),     gf = __shfl(act, 4 + u),
                    gg = __shfl(act, 8 + u), go = __shfl(act, 12 + u);
        const float cn = gf * c1b + gi * gg;
        const float hn = go * tanhf(cn);
        c1b = cn;
        publish(ring1, s + 1, b1v, slice, lane, hn);
      }
    }
    // epilogue: out[T-1] from h2[T] (tag TSTEPS), written by slice-0 blocks
    if (slice == 0) {
      f4 g0, g1;
      ok = poll2(recp(ring2, TSTEPS, b0, lane), recp(ring2, TSTEPS, b1v, lane),
                 (float)TSTEPS, g0, g1, ok);
      float po00 = g0.x * wo0[0] + g0.y * wo0[1] + g0.z * wo0[2] + g0.w * wo0[3];
      float po01 = g0.x * wo1[0] + g0.y * wo1[1] + g0.z * wo1[2] + g0.w * wo1[3];
      float po10 = g1.x * wo0[0] + g1.y * wo0[1] + g1.z * wo0[2] + g1.w * wo0[3];
      float po11 = g1.x * wo1[0] + g1.y * wo1[1] + g1.z * wo1[2] + g1.w * wo1[3];
      #pragma unroll
      for (int d = 1; d < 64; d <<= 1) {
        po00 += __shfl_xor(po00, d); po01 += __shfl_xor(po01, d);
        po10 += __shfl_xor(po10, d); po11 += __shfl_xor(po11, d);
      }
      if (lane == 0) {
        *(float2*)(dout + (b0  * TSTEPS + TSTEPS - 1) * 2) =
            make_float2(sigm(po00 + bo0), sigm(po01 + bo1));
        *(float2*)(dout + (b1v * TSTEPS + TSTEPS - 1) * 2) =
            make_float2(sigm(po10 + bo0), sigm(po11 + bo1));
      }
    }
  } else {
    // ---------------- layer-2 blocks ----------------
    float wk[64], wr[64];
    #pragma unroll
    for (int j = 0; j < 64; ++j) {
      wk[j] = K2[(64 * kk + j) * 1024 + gc];
      wr[j] = R2[(64 * kk + j) * 1024 + gc];
    }
    const float bb2 = b2[gc];
    float c2a = 0.f, c2b = 0.f;
    float* bh20 = buf;
    float* bh21 = buf + VECF;
    float* bh10 = buf + 2 * VECF;
    float* bh11 = buf + 3 * VECF;
    for (int s = 0; s < TSTEPS; ++s) {
      // h2[s] (stale-available; zeros at s==0) -> stage
      f4 g0 = {0.f, 0.f, 0.f, 0.f}, g1 = {0.f, 0.f, 0.f, 0.f};
      if (s > 0)
        ok = poll2(recp(ring2, s, b0, lane), recp(ring2, s, b1v, lane), (float)s, g0, g1, ok);
      *(f4*)(bh20 + kk * CH + 4 * c) = g0;
      *(f4*)(bh21 + kk * CH + 4 * c) = g1;
      // R2 dots while h1[s+1] is in flight
      float rx0 = 0.f, ry0 = 0.f, rz0 = 0.f, rw0 = 0.f;
      float rx1 = 0.f, ry1 = 0.f, rz1 = 0.f, rw1 = 0.f;
      #pragma unroll
      for (int j = 0; j < 16; ++j) {
        const f4 h0 = *(const f4*)(bh20 + kk * CH + 4 * j);
        const f4 h1 = *(const f4*)(bh21 + kk * CH + 4 * j);
        rx0 = fmaf(wr[4 * j + 0], h0.x, rx0); ry0 = fmaf(wr[4 * j + 1], h0.y, ry0);
        rz0 = fmaf(wr[4 * j + 2], h0.z, rz0); rw0 = fmaf(wr[4 * j + 3], h0.w, rw0);
        rx1 = fmaf(wr[4 * j + 0], h1.x, rx1); ry1 = fmaf(wr[4 * j + 1], h1.y, ry1);
        rz1 = fmaf(wr[4 * j + 2], h1.z, rz1); rw1 = fmaf(wr[4 * j + 3], h1.w, rw1);
      }
      // fresh dependency: h1[s+1]
      f4 d0, d1;
      ok = poll2(recp(ring1, s + 1, b0, lane), recp(ring1, s + 1, b1v, lane),
                 (float)(s + 1), d0, d1, ok);
      *(f4*)(bh10 + kk * CH + 4 * c) = d0;
      *(f4*)(bh11 + kk * CH + 4 * c) = d1;
      float kx0 = 0.f, ky0 = 0.f, kz0 = 0.f, kw0 = 0.f;
      float kx1 = 0.f, ky1 = 0.f, kz1 = 0.f, kw1 = 0.f;
      #pragma unroll
      for (int j = 0; j < 16; ++j) {
        const f4 h0 = *(const f4*)(bh10 + kk * CH + 4 * j);
        const f4 h1 = *(const f4*)(bh11 + kk * CH + 4 * j);
        kx0 = fmaf(wk[4 * j + 0], h0.x, kx0); ky0 = fmaf(wk[4 * j + 1], h0.y, ky0);
        kz0 = fmaf(wk[4 * j + 2], h0.z, kz0); kw0 = fmaf(wk[4 * j + 3], h0.w, kw0);
        kx1 = fmaf(wk[4 * j + 0], h1.x, kx1); ky1 = fmaf(wk[4 * j + 1], h1.y, ky1);
        kz1 = fmaf(wk[4 * j + 2], h1.z, kz1); kw1 = fmaf(wk[4 * j + 3], h1.w, kw1);
      }
      float part0 = ((rx0 + ry0) + (rz0 + rw0)) + ((kx0 + ky0) + (kz0 + kw0));
      float part1 = ((rx1 + ry1) + (rz1 + rw1)) + ((kx1 + ky1) + (kz1 + kw1));
      part0 += __shfl_down(part0, 16); part0 += __shfl_down(part0, 32);
      part1 += __shfl_down(part1, 16); part1 += __shfl_down(part1, 32);
      {
        const float z = part0 + bb2;
        const float act = (q == 2) ? tanhf(z) : sigm(z);
        const float gi = __shfl(act, u),     gf = __shfl(act, 4 + u),
                    gg = __shfl(act, 8 + u), go = __shfl(act, 12 + u);
        const float cn = gf * c2a + gi * gg;
        const float hn = go * tanhf(cn);
        c2a = cn;
        publish(ring2, s + 1, b0, slice, lane, hn);
      }
      {
        const float z = part1 + bb2;
        const float act = (q == 2) ? tanhf(z) : sigm(z);
        const float gi = __shfl(act, u),     gf = __shfl(act, 4 + u),
                    gg = __shfl(act, 8 + u), go = __shfl(act, 12 + u);
        const float cn = gf * c2b + gi * gg;
        const float hn = go * tanhf(cn);
        c2b = cn;
        publish(ring2, s + 1, b1v, slice, lane, hn);
      }
    }
  }
  (void)ok;
}

extern "C" void kernel_launch(void* const* d_in, const int* in_sizes, int n_in,
                              void* d_out, int out_size, void* d_ws, size_t ws_size,
                              hipStream_t stream) {
  (void)in_sizes; (void)n_in; (void)out_size; (void)ws_size;
  const float* ctx = (const float*)d_in[0];
  const float* Wc  = (const float*)d_in[1];
  const float* bc  = (const float*)d_in[2];
  const float* K1  = (const float*)d_in[3];
  const float* R1  = (const float*)d_in[4];
  const float* b1  = (const float*)d_in[5];
  const float* K2  = (const float*)d_in[6];
  const float* R2  = (const float*)d_in[7];
  const float* b2  = (const float*)d_in[8];
  const float* Wo  = (const float*)d_in[9];
  const float* bo  = (const float*)d_in[10];

  float* ring1 = (float*)d_ws;                 // [2][NB][NSL][8] = 128 KiB
  float* ring2 = ring1 + 2 * NB * NSL * RECF;  // [2][NB][NSL][8] = 128 KiB
  // No flag reset needed: records are self-validating (checksum+tag), and any
  // leftover/poison content either fails validation or is a bit-identical
  // record from the previous (deterministic) run.

  hipFuncSetAttribute((const void*)swd_kernel,
                      hipFuncAttributeMaxDynamicSharedMemorySize, SMEM_BYTES);
  swd_kernel<<<dim3(256), dim3(NTHR), SMEM_BYTES, stream>>>(
      ctx, Wc, bc, K1, R1, b1, K2, R2, b2, Wo, bo,
      (float*)d_out, ring1, ring2);
}